// Round 1
// baseline (178.179 us; speedup 1.0000x reference)
//
#include <hip/hip_runtime.h>
#include <cstdint>
#include <cmath>

#define NTHREADS 1024
#define B_ROWS 256
#define V_COLS 128000
#define V4 (V_COLS / 4)

__device__ __forceinline__ uint32_t rotl32(uint32_t x, uint32_t d) {
  return (x << d) | (x >> (32u - d));
}

// threefry2x32 with key (0, 42), returns XOR of the two outputs
// (JAX partitionable-threefry bit stream for 32-bit draws).
__device__ __forceinline__ uint32_t threefry_xor(uint32_t x0, uint32_t x1) {
  const uint32_t k0 = 0u;
  const uint32_t k1 = 42u;
  const uint32_t k2 = 0x1BD11BDAu ^ k0 ^ k1;  // 0x1BD11BF0
  x0 += k0; x1 += k1;
#define TF_RND(r) { x0 += x1; x1 = rotl32(x1, (r)); x1 ^= x0; }
  TF_RND(13) TF_RND(15) TF_RND(26) TF_RND(6)
  x0 += k1; x1 += k2 + 1u;
  TF_RND(17) TF_RND(29) TF_RND(16) TF_RND(24)
  x0 += k2; x1 += k0 + 2u;
  TF_RND(13) TF_RND(15) TF_RND(26) TF_RND(6)
  x0 += k0; x1 += k1 + 3u;
  TF_RND(17) TF_RND(29) TF_RND(16) TF_RND(24)
  x0 += k1; x1 += k2 + 4u;
  TF_RND(13) TF_RND(15) TF_RND(26) TF_RND(6)
  x0 += k2; x1 += k0 + 5u;
#undef TF_RND
  return x0 ^ x1;
}

__device__ __forceinline__ float gumbel_from_bits(uint32_t bits) {
  // JAX uniform(tiny, 1): f in [0,1) from top-23 mantissa bits; max with tiny.
  uint32_t ub = (bits >> 9) | 0x3f800000u;
  float f = __uint_as_float(ub) - 1.0f;
  float u = fmaxf(f, 1.17549435e-38f);
  return -logf(-logf(u));
}

__global__ __launch_bounds__(NTHREADS) void sampler_kernel(
    const float* __restrict__ logits,
    const float* __restrict__ temps,
    float* __restrict__ out) {
  const int b = blockIdx.x;
  const int tid = threadIdx.x;
  const float t = temps[b];
  const float tsafe = (t == 0.0f) ? 1.0f : t;
  const float* __restrict__ row = logits + (size_t)b * V_COLS;
  float* __restrict__ prow = out + B_ROWS + (size_t)b * V_COLS;

  // greedy argmax over ORIGINAL logits
  float gmax = -INFINITY; int gidx = 0;
  // sample argmax over gumbel + scaled
  float smax = -INFINITY; int sidx = 0;
  // online softmax over scaled
  float m = -INFINITY; float s = 0.0f;

  const uint32_t cbase = (uint32_t)b * (uint32_t)V_COLS;

  for (int i = tid; i < V4; i += NTHREADS) {
    const float4 x4 = reinterpret_cast<const float4*>(row)[i];
    const float xa[4] = {x4.x, x4.y, x4.z, x4.w};
#pragma unroll
    for (int k = 0; k < 4; ++k) {
      const float x = xa[k];
      const int v = i * 4 + k;
      if (x > gmax) { gmax = x; gidx = v; }
      const float sx = x / tsafe;
      const float mn = fmaxf(m, sx);
      s = s * expf(m - mn) + expf(sx - mn);
      m = mn;
      const uint32_t bits = threefry_xor(0u, cbase + (uint32_t)v);
      const float cand = gumbel_from_bits(bits) + sx;
      if (cand > smax) { smax = cand; sidx = v; }
    }
  }

  // wave-level butterfly reduce (64 lanes); tie -> lower index (np.argmax)
#pragma unroll
  for (int off = 32; off > 0; off >>= 1) {
    float ov = __shfl_xor(gmax, off);
    int   oi = __shfl_xor(gidx, off);
    if (ov > gmax || (ov == gmax && oi < gidx)) { gmax = ov; gidx = oi; }
    float osv = __shfl_xor(smax, off);
    int   osi = __shfl_xor(sidx, off);
    if (osv > smax || (osv == smax && osi < sidx)) { smax = osv; sidx = osi; }
    float om = __shfl_xor(m, off);
    float os = __shfl_xor(s, off);
    float mn = fmaxf(m, om);
    s = s * expf(m - mn) + os * expf(om - mn);
    m = mn;
  }

  __shared__ float lds_gv[NTHREADS / 64]; __shared__ int lds_gi[NTHREADS / 64];
  __shared__ float lds_sv[NTHREADS / 64]; __shared__ int lds_si[NTHREADS / 64];
  __shared__ float lds_m[NTHREADS / 64];  __shared__ float lds_s[NTHREADS / 64];
  __shared__ float fin_m, fin_s;

  const int wid = tid >> 6;
  const int lane = tid & 63;
  if (lane == 0) {
    lds_gv[wid] = gmax; lds_gi[wid] = gidx;
    lds_sv[wid] = smax; lds_si[wid] = sidx;
    lds_m[wid] = m;     lds_s[wid] = s;
  }
  __syncthreads();
  if (tid == 0) {
    float Gv = lds_gv[0]; int Gi = lds_gi[0];
    float Sv = lds_sv[0]; int Si = lds_si[0];
    float M = lds_m[0];   float S = lds_s[0];
#pragma unroll
    for (int w = 1; w < NTHREADS / 64; ++w) {
      float ov = lds_gv[w]; int oi = lds_gi[w];
      if (ov > Gv || (ov == Gv && oi < Gi)) { Gv = ov; Gi = oi; }
      float osv = lds_sv[w]; int osi = lds_si[w];
      if (osv > Sv || (osv == Sv && osi < Si)) { Sv = osv; Si = osi; }
      float om = lds_m[w]; float os = lds_s[w];
      float mn = fmaxf(M, om);
      S = S * expf(M - mn) + os * expf(om - mn);
      M = mn;
    }
    const int token = (t == 0.0f) ? Gi : Si;
    out[b] = (float)token;          // tokens stored as f32 values
    fin_m = M; fin_s = S;
  }
  __syncthreads();
  const float M = fin_m;
  const float S = fin_s;

  // phase 2: probs = exp(scaled - max) / sum
  for (int i = tid; i < V4; i += NTHREADS) {
    const float4 x4 = reinterpret_cast<const float4*>(row)[i];
    float4 p4;
    p4.x = expf(x4.x / tsafe - M) / S;
    p4.y = expf(x4.y / tsafe - M) / S;
    p4.z = expf(x4.z / tsafe - M) / S;
    p4.w = expf(x4.w / tsafe - M) / S;
    reinterpret_cast<float4*>(prow)[i] = p4;
  }
}

extern "C" void kernel_launch(void* const* d_in, const int* in_sizes, int n_in,
                              void* d_out, int out_size, void* d_ws, size_t ws_size,
                              hipStream_t stream) {
  const float* logits = (const float*)d_in[0];
  const float* temps  = (const float*)d_in[1];
  float* out = (float*)d_out;
  sampler_kernel<<<B_ROWS, NTHREADS, 0, stream>>>(logits, temps, out);
}

// Round 2
// 154.143 us; speedup vs baseline: 1.1559x; 1.1559x over previous
//
#include <hip/hip_runtime.h>
#include <cstdint>
#include <cmath>

#define NTHREADS 1024
#define B_ROWS 256
#define V_COLS 128000
#define V4 (V_COLS / 4)

__device__ __forceinline__ uint32_t rotl32(uint32_t x, uint32_t d) {
  return (x << d) | (x >> (32u - d));
}

// threefry2x32 with key (0, 42), returns XOR of the two outputs
// (JAX partitionable-threefry bit stream for 32-bit draws).
__device__ __forceinline__ uint32_t threefry_xor(uint32_t x0, uint32_t x1) {
  const uint32_t k0 = 0u;
  const uint32_t k1 = 42u;
  const uint32_t k2 = 0x1BD11BDAu ^ k0 ^ k1;  // 0x1BD11BF0
  x0 += k0; x1 += k1;
#define TF_RND(r) { x0 += x1; x1 = rotl32(x1, (r)); x1 ^= x0; }
  TF_RND(13) TF_RND(15) TF_RND(26) TF_RND(6)
  x0 += k1; x1 += k2 + 1u;
  TF_RND(17) TF_RND(29) TF_RND(16) TF_RND(24)
  x0 += k2; x1 += k0 + 2u;
  TF_RND(13) TF_RND(15) TF_RND(26) TF_RND(6)
  x0 += k0; x1 += k1 + 3u;
  TF_RND(17) TF_RND(29) TF_RND(16) TF_RND(24)
  x0 += k1; x1 += k2 + 4u;
  TF_RND(13) TF_RND(15) TF_RND(26) TF_RND(6)
  x0 += k2; x1 += k0 + 5u;
#undef TF_RND
  return x0 ^ x1;
}

__device__ __forceinline__ float gumbel_from_bits(uint32_t bits) {
  // JAX uniform(tiny, 1): f in [0,1) from top-23 mantissa bits; max with tiny.
  uint32_t ub = (bits >> 9) | 0x3f800000u;
  float f = __uint_as_float(ub) - 1.0f;
  float u = fmaxf(f, 1.17549435e-38f);
  // token-determining path: keep accurate libm logf (matched reference in R1)
  return -logf(-logf(u));
}

__global__ __launch_bounds__(NTHREADS) void sampler_kernel(
    const float* __restrict__ logits,
    const float* __restrict__ temps,
    float* __restrict__ out) {
  const int b = blockIdx.x;
  const int tid = threadIdx.x;
  const float t = temps[b];
  const float tsafe = (t == 0.0f) ? 1.0f : t;
  const float inv_t = 1.0f / tsafe;
  const float* __restrict__ row = logits + (size_t)b * V_COLS;
  float* __restrict__ prow = out + B_ROWS + (size_t)b * V_COLS;

  // greedy argmax over ORIGINAL logits
  float gmax = -INFINITY; int gidx = 0;
  // sample argmax over gumbel + scaled
  float smax = -INFINITY; int sidx = 0;
  // online softmax over scaled (branchless, native exp — probs-only path)
  float m = -INFINITY; float s = 0.0f;

  const uint32_t cbase = (uint32_t)b * (uint32_t)V_COLS;

  for (int i = tid; i < V4; i += NTHREADS) {
    const float4 x4 = reinterpret_cast<const float4*>(row)[i];
    const float xa[4] = {x4.x, x4.y, x4.z, x4.w};
    const uint32_t c0 = cbase + (uint32_t)(i * 4);
#pragma unroll
    for (int k = 0; k < 4; ++k) {
      const float x = xa[k];
      const int v = i * 4 + k;
      if (x > gmax) { gmax = x; gidx = v; }
      const float sx = x * inv_t;
      const float mn = fmaxf(m, sx);
      s = fmaf(s, __expf(m - mn), __expf(sx - mn));
      m = mn;
      const uint32_t bits = threefry_xor(0u, c0 + (uint32_t)k);
      const float cand = gumbel_from_bits(bits) + sx;
      if (cand > smax) { smax = cand; sidx = v; }
    }
  }

  // wave-level butterfly reduce (64 lanes); tie -> lower index (np.argmax)
#pragma unroll
  for (int off = 32; off > 0; off >>= 1) {
    float ov = __shfl_xor(gmax, off);
    int   oi = __shfl_xor(gidx, off);
    if (ov > gmax || (ov == gmax && oi < gidx)) { gmax = ov; gidx = oi; }
    float osv = __shfl_xor(smax, off);
    int   osi = __shfl_xor(sidx, off);
    if (osv > smax || (osv == smax && osi < sidx)) { smax = osv; sidx = osi; }
    float om = __shfl_xor(m, off);
    float os = __shfl_xor(s, off);
    float mn = fmaxf(m, om);
    s = fmaf(s, __expf(m - mn), os * __expf(om - mn));
    m = mn;
  }

  __shared__ float lds_gv[NTHREADS / 64]; __shared__ int lds_gi[NTHREADS / 64];
  __shared__ float lds_sv[NTHREADS / 64]; __shared__ int lds_si[NTHREADS / 64];
  __shared__ float lds_m[NTHREADS / 64];  __shared__ float lds_s[NTHREADS / 64];
  __shared__ float fin_m, fin_s;

  const int wid = tid >> 6;
  const int lane = tid & 63;
  if (lane == 0) {
    lds_gv[wid] = gmax; lds_gi[wid] = gidx;
    lds_sv[wid] = smax; lds_si[wid] = sidx;
    lds_m[wid] = m;     lds_s[wid] = s;
  }
  __syncthreads();
  if (tid == 0) {
    float Gv = lds_gv[0]; int Gi = lds_gi[0];
    float Sv = lds_sv[0]; int Si = lds_si[0];
    float M = lds_m[0];   float S = lds_s[0];
#pragma unroll
    for (int w = 1; w < NTHREADS / 64; ++w) {
      float ov = lds_gv[w]; int oi = lds_gi[w];
      if (ov > Gv || (ov == Gv && oi < Gi)) { Gv = ov; Gi = oi; }
      float osv = lds_sv[w]; int osi = lds_si[w];
      if (osv > Sv || (osv == Sv && osi < Si)) { Sv = osv; Si = osi; }
      float om = lds_m[w]; float os = lds_s[w];
      float mn = fmaxf(M, om);
      S = fmaf(S, __expf(M - mn), os * __expf(om - mn));
      M = mn;
    }
    const int token = (t == 0.0f) ? Gi : Si;
    out[b] = (float)token;          // tokens stored as f32 values
    fin_m = M; fin_s = S;
  }
  __syncthreads();
  const float M = fin_m;
  const float invS = 1.0f / fin_s;

  // phase 2: probs = exp(x*inv_t - M) * invS  (native exp, fma-folded arg)
  for (int i = tid; i < V4; i += NTHREADS) {
    const float4 x4 = reinterpret_cast<const float4*>(row)[i];
    float4 p4;
    p4.x = __expf(fmaf(x4.x, inv_t, -M)) * invS;
    p4.y = __expf(fmaf(x4.y, inv_t, -M)) * invS;
    p4.z = __expf(fmaf(x4.z, inv_t, -M)) * invS;
    p4.w = __expf(fmaf(x4.w, inv_t, -M)) * invS;
    reinterpret_cast<float4*>(prow)[i] = p4;
  }
}

extern "C" void kernel_launch(void* const* d_in, const int* in_sizes, int n_in,
                              void* d_out, int out_size, void* d_ws, size_t ws_size,
                              hipStream_t stream) {
  const float* logits = (const float*)d_in[0];
  const float* temps  = (const float*)d_in[1];
  float* out = (float*)d_out;
  sampler_kernel<<<B_ROWS, NTHREADS, 0, stream>>>(logits, temps, out);
}

// Round 3
// 140.429 us; speedup vs baseline: 1.2688x; 1.0977x over previous
//
#include <hip/hip_runtime.h>
#include <cstdint>
#include <cmath>

#define NTHREADS 1024
#define B_ROWS 256
#define V_COLS 128000
#define V4 (V_COLS / 4)

__device__ __forceinline__ uint32_t rotl32(uint32_t x, uint32_t d) {
  return (x << d) | (x >> (32u - d));
}

// threefry2x32 with key (0, 42), returns XOR of the two outputs
// (JAX partitionable-threefry bit stream for 32-bit draws).
__device__ __forceinline__ uint32_t threefry_xor(uint32_t x0, uint32_t x1) {
  const uint32_t k0 = 0u;
  const uint32_t k1 = 42u;
  const uint32_t k2 = 0x1BD11BDAu ^ k0 ^ k1;  // 0x1BD11BF0
  x0 += k0; x1 += k1;
#define TF_RND(r) { x0 += x1; x1 = rotl32(x1, (r)); x1 ^= x0; }
  TF_RND(13) TF_RND(15) TF_RND(26) TF_RND(6)
  x0 += k1; x1 += k2 + 1u;
  TF_RND(17) TF_RND(29) TF_RND(16) TF_RND(24)
  x0 += k2; x1 += k0 + 2u;
  TF_RND(13) TF_RND(15) TF_RND(26) TF_RND(6)
  x0 += k0; x1 += k1 + 3u;
  TF_RND(17) TF_RND(29) TF_RND(16) TF_RND(24)
  x0 += k1; x1 += k2 + 4u;
  TF_RND(13) TF_RND(15) TF_RND(26) TF_RND(6)
  x0 += k2; x1 += k0 + 5u;
#undef TF_RND
  return x0 ^ x1;
}

#define LN2F 0.69314718055994530942f

__device__ __forceinline__ float gumbel_from_bits(uint32_t bits) {
  // JAX uniform(tiny, 1): f in [0,1) from top-23 mantissa bits; max with tiny.
  uint32_t ub = (bits >> 9) | 0x3f800000u;
  float f = __uint_as_float(ub) - 1.0f;
  float u = fmaxf(f, 1.17549435e-38f);
  // -log(-log(u)) via native v_log_f32 (log2), ln x = ln2 * log2 x.
  // u in [tiny, 1-2^-24]: no specials on either log. ~1e-6 abs error vs
  // libm — far under the ~4e-3 min top-2 gumbel margin across 256 rows.
  const float l1 = __log2f(u);          // <= ~-1.2e-7, >= ~-126
  const float nl = -LN2F * l1;          // -ln(u) in (1e-7, 88]
  const float l2 = __log2f(nl);
  return -LN2F * l2;
}

__global__ __launch_bounds__(NTHREADS) void sampler_kernel(
    const float* __restrict__ logits,
    const float* __restrict__ temps,
    float* __restrict__ out) {
  const int b = blockIdx.x;
  const int tid = threadIdx.x;
  const float t = temps[b];
  const float tsafe = (t == 0.0f) ? 1.0f : t;
  const float inv_t = 1.0f / tsafe;
  const float* __restrict__ row = logits + (size_t)b * V_COLS;
  float* __restrict__ prow = out + B_ROWS + (size_t)b * V_COLS;

  // greedy argmax over ORIGINAL logits
  float gmax = -INFINITY; int gidx = 0;
  // sample argmax over gumbel + scaled
  float smax = -INFINITY; int sidx = 0;
  // online softmax over scaled (branchless, native exp — probs-only path)
  float m = -INFINITY; float s = 0.0f;

  const uint32_t cbase = (uint32_t)b * (uint32_t)V_COLS;

  for (int i = tid; i < V4; i += NTHREADS) {
    const float4 x4 = reinterpret_cast<const float4*>(row)[i];
    const float xa[4] = {x4.x, x4.y, x4.z, x4.w};
    const uint32_t c0 = cbase + (uint32_t)(i * 4);
#pragma unroll
    for (int k = 0; k < 4; ++k) {
      const float x = xa[k];
      const int v = i * 4 + k;
      if (x > gmax) { gmax = x; gidx = v; }
      const float sx = x * inv_t;
      const float mn = fmaxf(m, sx);
      s = fmaf(s, __expf(m - mn), __expf(sx - mn));
      m = mn;
      const uint32_t bits = threefry_xor(0u, c0 + (uint32_t)k);
      const float cand = gumbel_from_bits(bits) + sx;
      if (cand > smax) { smax = cand; sidx = v; }
    }
  }

  // wave-level butterfly reduce (64 lanes); tie -> lower index (np.argmax)
#pragma unroll
  for (int off = 32; off > 0; off >>= 1) {
    float ov = __shfl_xor(gmax, off);
    int   oi = __shfl_xor(gidx, off);
    if (ov > gmax || (ov == gmax && oi < gidx)) { gmax = ov; gidx = oi; }
    float osv = __shfl_xor(smax, off);
    int   osi = __shfl_xor(sidx, off);
    if (osv > smax || (osv == smax && osi < sidx)) { smax = osv; sidx = osi; }
    float om = __shfl_xor(m, off);
    float os = __shfl_xor(s, off);
    float mn = fmaxf(m, om);
    s = fmaf(s, __expf(m - mn), os * __expf(om - mn));
    m = mn;
  }

  __shared__ float lds_gv[NTHREADS / 64]; __shared__ int lds_gi[NTHREADS / 64];
  __shared__ float lds_sv[NTHREADS / 64]; __shared__ int lds_si[NTHREADS / 64];
  __shared__ float lds_m[NTHREADS / 64];  __shared__ float lds_s[NTHREADS / 64];
  __shared__ float fin_m, fin_s;

  const int wid = tid >> 6;
  const int lane = tid & 63;
  if (lane == 0) {
    lds_gv[wid] = gmax; lds_gi[wid] = gidx;
    lds_sv[wid] = smax; lds_si[wid] = sidx;
    lds_m[wid] = m;     lds_s[wid] = s;
  }
  __syncthreads();
  if (tid == 0) {
    float Gv = lds_gv[0]; int Gi = lds_gi[0];
    float Sv = lds_sv[0]; int Si = lds_si[0];
    float M = lds_m[0];   float S = lds_s[0];
#pragma unroll
    for (int w = 1; w < NTHREADS / 64; ++w) {
      float ov = lds_gv[w]; int oi = lds_gi[w];
      if (ov > Gv || (ov == Gv && oi < Gi)) { Gv = ov; Gi = oi; }
      float osv = lds_sv[w]; int osi = lds_si[w];
      if (osv > Sv || (osv == Sv && osi < Si)) { Sv = osv; Si = osi; }
      float om = lds_m[w]; float os = lds_s[w];
      float mn = fmaxf(M, om);
      S = fmaf(S, __expf(M - mn), os * __expf(om - mn));
      M = mn;
    }
    const int token = (t == 0.0f) ? Gi : Si;
    out[b] = (float)token;          // tokens stored as f32 values
    fin_m = M; fin_s = S;
  }
  __syncthreads();
  const float M = fin_m;
  const float invS = 1.0f / fin_s;

  // phase 2: probs = exp(x*inv_t - M) * invS  (native exp, fma-folded arg)
  for (int i = tid; i < V4; i += NTHREADS) {
    const float4 x4 = reinterpret_cast<const float4*>(row)[i];
    float4 p4;
    p4.x = __expf(fmaf(x4.x, inv_t, -M)) * invS;
    p4.y = __expf(fmaf(x4.y, inv_t, -M)) * invS;
    p4.z = __expf(fmaf(x4.z, inv_t, -M)) * invS;
    p4.w = __expf(fmaf(x4.w, inv_t, -M)) * invS;
    reinterpret_cast<float4*>(prow)[i] = p4;
  }
}

extern "C" void kernel_launch(void* const* d_in, const int* in_sizes, int n_in,
                              void* d_out, int out_size, void* d_ws, size_t ws_size,
                              hipStream_t stream) {
  const float* logits = (const float*)d_in[0];
  const float* temps  = (const float*)d_in[1];
  float* out = (float*)d_out;
  sampler_kernel<<<B_ROWS, NTHREADS, 0, stream>>>(logits, temps, out);
}

// Round 4
// 135.922 us; speedup vs baseline: 1.3109x; 1.0332x over previous
//
#include <hip/hip_runtime.h>
#include <cstdint>
#include <cmath>

#define NTHREADS 1024
#define B_ROWS 256
#define V_COLS 128000
#define V4 (V_COLS / 4)
#define NWAVES (NTHREADS / 64)
#define LN2F 0.69314718055994530942f

// single-instruction rotate: alignbit(x,x,32-d) == rotr(x,32-d) == rotl(x,d)
__device__ __forceinline__ uint32_t rotl32(uint32_t x, uint32_t d) {
  return __builtin_amdgcn_alignbit(x, x, 32u - d);
}

// threefry2x32 with key (0, 42), XOR of the two outputs
// (JAX partitionable-threefry bit stream for 32-bit draws).
__device__ __forceinline__ uint32_t threefry_xor(uint32_t x0, uint32_t x1) {
  const uint32_t k0 = 0u;
  const uint32_t k1 = 42u;
  const uint32_t k2 = 0x1BD11BDAu ^ k0 ^ k1;  // 0x1BD11BF0
  x0 += k0; x1 += k1;
#define TF_RND(r) { x0 += x1; x1 = rotl32(x1, (r)); x1 ^= x0; }
  TF_RND(13) TF_RND(15) TF_RND(26) TF_RND(6)
  x0 += k1; x1 += k2 + 1u;
  TF_RND(17) TF_RND(29) TF_RND(16) TF_RND(24)
  x0 += k2; x1 += k0 + 2u;
  TF_RND(13) TF_RND(15) TF_RND(26) TF_RND(6)
  x0 += k0; x1 += k1 + 3u;
  TF_RND(17) TF_RND(29) TF_RND(16) TF_RND(24)
  x0 += k1; x1 += k2 + 4u;
  TF_RND(13) TF_RND(15) TF_RND(26) TF_RND(6)
  x0 += k2; x1 += k0 + 5u;
#undef TF_RND
  return x0 ^ x1;
}

// returns l2 with gumbel == -LN2F * l2  (caller folds into fma with sx)
__device__ __forceinline__ float gumbel_l2(uint32_t bits) {
  uint32_t ub = (bits >> 9) | 0x3f800000u;
  float f = __uint_as_float(ub) - 1.0f;
  float u = fmaxf(f, 1.17549435e-38f);
  const float l1 = __log2f(u);
  const float nl = -LN2F * l1;
  return __log2f(nl);
}

__global__ __launch_bounds__(NTHREADS) void sampler_kernel(
    const float* __restrict__ logits,
    const float* __restrict__ temps,
    float* __restrict__ out) {
  const int b = blockIdx.x;
  const int tid = threadIdx.x;
  const float t = temps[b];
  const float tsafe = (t == 0.0f) ? 1.0f : t;
  const float inv_t = 1.0f / tsafe;
  const float* __restrict__ row = logits + (size_t)b * V_COLS;
  float* __restrict__ prow = out + B_ROWS + (size_t)b * V_COLS;

  float gmax = -INFINITY; int gidx = 0;   // greedy (value always; index only t==0 path)
  float smax = -INFINITY; int sidx = 0;   // gumbel sample argmax
  float m = -INFINITY, s = 0.0f;          // online softmax (batched per float4)

  const uint32_t cbase = (uint32_t)b * (uint32_t)V_COLS;

  if (t != 0.0f) {
    // hot path: no greedy index, gumbel sampling active
    for (int i = tid; i < V4; i += NTHREADS) {
      const float4 x4 = reinterpret_cast<const float4*>(row)[i];
      const uint32_t c0 = cbase + (uint32_t)(i * 4);
      const float sx0 = x4.x * inv_t;
      const float sx1 = x4.y * inv_t;
      const float sx2 = x4.z * inv_t;
      const float sx3 = x4.w * inv_t;
      {
        const float c = fmaf(-LN2F, gumbel_l2(threefry_xor(0u, c0 + 0u)), sx0);
        if (c > smax) { smax = c; sidx = i * 4 + 0; }
      }
      {
        const float c = fmaf(-LN2F, gumbel_l2(threefry_xor(0u, c0 + 1u)), sx1);
        if (c > smax) { smax = c; sidx = i * 4 + 1; }
      }
      {
        const float c = fmaf(-LN2F, gumbel_l2(threefry_xor(0u, c0 + 2u)), sx2);
        if (c > smax) { smax = c; sidx = i * 4 + 2; }
      }
      {
        const float c = fmaf(-LN2F, gumbel_l2(threefry_xor(0u, c0 + 3u)), sx3);
        if (c > smax) { smax = c; sidx = i * 4 + 3; }
      }
      // shared raw-max; round-monotone: max(sx_i) == mx4*inv_t bitwise
      const float mx4 = fmaxf(fmaxf(x4.x, x4.y), fmaxf(x4.z, x4.w));
      gmax = fmaxf(gmax, mx4);
      const float mn = fmaxf(m, mx4 * inv_t);
      s = fmaf(s, __expf(m - mn),
               __expf(sx0 - mn) + __expf(sx1 - mn) +
               __expf(sx2 - mn) + __expf(sx3 - mn));
      m = mn;
    }
  } else {
    // greedy path: full first-index argmax, no RNG needed
    for (int i = tid; i < V4; i += NTHREADS) {
      const float4 x4 = reinterpret_cast<const float4*>(row)[i];
      if (x4.x > gmax) { gmax = x4.x; gidx = i * 4 + 0; }
      if (x4.y > gmax) { gmax = x4.y; gidx = i * 4 + 1; }
      if (x4.z > gmax) { gmax = x4.z; gidx = i * 4 + 2; }
      if (x4.w > gmax) { gmax = x4.w; gidx = i * 4 + 3; }
      const float mx4 = fmaxf(fmaxf(x4.x, x4.y), fmaxf(x4.z, x4.w));
      const float mn = fmaxf(m, mx4);   // inv_t == 1
      s = fmaf(s, __expf(m - mn),
               __expf(x4.x - mn) + __expf(x4.y - mn) +
               __expf(x4.z - mn) + __expf(x4.w - mn));
      m = mn;
    }
  }

  // wave-level butterfly reduce; ties -> lower index (np.argmax)
#pragma unroll
  for (int off = 32; off > 0; off >>= 1) {
    float ov = __shfl_xor(gmax, off);
    int   oi = __shfl_xor(gidx, off);
    if (ov > gmax || (ov == gmax && oi < gidx)) { gmax = ov; gidx = oi; }
    float osv = __shfl_xor(smax, off);
    int   osi = __shfl_xor(sidx, off);
    if (osv > smax || (osv == smax && osi < sidx)) { smax = osv; sidx = osi; }
    float om = __shfl_xor(m, off);
    float os = __shfl_xor(s, off);
    float mn = fmaxf(m, om);
    s = fmaf(s, __expf(m - mn), os * __expf(om - mn));
    m = mn;
  }

  __shared__ float lds_gv[NWAVES]; __shared__ int lds_gi[NWAVES];
  __shared__ float lds_sv[NWAVES]; __shared__ int lds_si[NWAVES];
  __shared__ float lds_m[NWAVES];  __shared__ float lds_s[NWAVES];
  __shared__ float fin_m, fin_invS;

  const int wid = tid >> 6;
  const int lane = tid & 63;
  if (lane == 0) {
    lds_gv[wid] = gmax; lds_gi[wid] = gidx;
    lds_sv[wid] = smax; lds_si[wid] = sidx;
    lds_m[wid] = m;     lds_s[wid] = s;
  }
  __syncthreads();
  if (tid == 0) {
    float Gv = lds_gv[0]; int Gi = lds_gi[0];
    float Sv = lds_sv[0]; int Si = lds_si[0];
    float M = lds_m[0];   float S = lds_s[0];
#pragma unroll
    for (int w = 1; w < NWAVES; ++w) {
      float ov = lds_gv[w]; int oi = lds_gi[w];
      if (ov > Gv || (ov == Gv && oi < Gi)) { Gv = ov; Gi = oi; }
      float osv = lds_sv[w]; int osi = lds_si[w];
      if (osv > Sv || (osv == Sv && osi < Si)) { Sv = osv; Si = osi; }
      float om = lds_m[w]; float os = lds_s[w];
      float mn = fmaxf(M, om);
      S = fmaf(S, __expf(M - mn), os * __expf(om - mn));
      M = mn;
    }
    const int token = (t == 0.0f) ? Gi : Si;
    out[b] = (float)token;          // tokens stored as f32 values
    fin_m = M; fin_invS = 1.0f / S;
  }
  __syncthreads();
  const float M = fin_m;
  const float invS = fin_invS;

  // pass 2: probs = exp(x*inv_t - M) * invS  (native exp, fma-folded arg)
  for (int i = tid; i < V4; i += NTHREADS) {
    const float4 x4 = reinterpret_cast<const float4*>(row)[i];
    float4 p4;
    p4.x = __expf(fmaf(x4.x, inv_t, -M)) * invS;
    p4.y = __expf(fmaf(x4.y, inv_t, -M)) * invS;
    p4.z = __expf(fmaf(x4.z, inv_t, -M)) * invS;
    p4.w = __expf(fmaf(x4.w, inv_t, -M)) * invS;
    reinterpret_cast<float4*>(prow)[i] = p4;
  }
}

extern "C" void kernel_launch(void* const* d_in, const int* in_sizes, int n_in,
                              void* d_out, int out_size, void* d_ws, size_t ws_size,
                              hipStream_t stream) {
  const float* logits = (const float*)d_in[0];
  const float* temps  = (const float*)d_in[1];
  float* out = (float*)d_out;
  sampler_kernel<<<B_ROWS, NTHREADS, 0, stream>>>(logits, temps, out);
}